// Round 26
// baseline (57.484 us; speedup 1.0000x reference)
//
#include <hip/hip_runtime.h>
#include <hip/hip_bf16.h>

#define N 8192        // n_users == n_recipes (required by reference broadcasting)
#define D 64
#define B_PAIRS 65536
#define FILL 0.1f
#define LOG2E 1.4426950408889634f
#define LN2 0.6931471805599453
#define RSP_STRIDE 36   // row-partial LDS stride (floats): 16B-aligned, 2-way banks

typedef __attribute__((ext_vector_type(8))) short short8v;   // 8 bf16 in 4 VGPRs
typedef __attribute__((ext_vector_type(4))) float f32x4;

__device__ __forceinline__ float wave_reduce_sum(float v) {
  #pragma unroll
  for (int m = 1; m < 64; m <<= 1) v += __shfl_xor(v, m, 64);
  return v;
}

__device__ __forceinline__ float bf16_to_f32(unsigned short u) {
  unsigned int b = ((unsigned int)u) << 16;
  return __builtin_bit_cast(float, b);
}

__device__ __forceinline__ short f32_bf16_rne(float f) {
  unsigned int b = __builtin_bit_cast(unsigned int, f);
  return (short)((b + 0x7FFFu + ((b >> 16) & 1u)) >> 16);
}

// v_exp_f32 via builtin (compiler handles the trans-op wait states; raw asm
// without s_nop corrupted results in R8). Args bounded: |x| <= ~1.45.
__device__ __forceinline__ float fast_exp2(float x) {
#if __has_builtin(__builtin_amdgcn_exp2f)
  return __builtin_amdgcn_exp2f(x);
#else
  float r;
  asm("v_exp_f32 %0, %1\n\ts_nop 1" : "=v"(r) : "v"(x));
  return r;
#endif
}

// Vectorized norm. Emits TWO copies of the normalized bf16 rows:
//  (a) row-major (for the scatter/colsum aux sections), and
//  (b) FRAGMENT-LINEAR: each 16-row tile stored chunk-order (ks,kgrp,lrow)
//      so a gemm fragment load is base + lane*16B (R23: -27% total).
// U side pre-scaled by log2(e) so the gemm uses raw exp2.
// Side duty: zero-init accumulators + completion counter (replay-safe).
__global__ __launch_bounds__(256) void norm_kernel(const float* __restrict__ U,
                                                   const float* __restrict__ R,
                                                   short* __restrict__ Ub,
                                                   short* __restrict__ Rb,
                                                   short* __restrict__ Ubp,
                                                   short* __restrict__ Rbp,
                                                   float* __restrict__ rowRMe,
                                                   float* __restrict__ sumU,
                                                   float* __restrict__ sumR,
                                                   double* __restrict__ scal) {
  const int t = threadIdx.x;
  const int b = blockIdx.x;
  if (b < 32) {
    rowRMe[b * 256 + t] = 0.f;
  } else if (b == 32) {
    if (t < 64) sumU[t] = 0.f;
    else if (t < 128) sumR[t - 64] = 0.f;
    else if (t < 136) scal[t - 128] = 0.0;   // scal[0..7]; [7] doubles as counter
  }
  int row = b * 16 + (t >> 4);               // 16 rows/block
  int c = t & 15;                            // float4 index within row (k=4c..4c+3)
  bool isU = row < N;
  int lrow = row & 15;
  const float* src = isU ? (U + (size_t)row * D) : (R + (size_t)(row - N) * D);
  float4 v = reinterpret_cast<const float4*>(src)[c];
  float ss = v.x * v.x + v.y * v.y + v.z * v.z + v.w * v.w;
  ss += __shfl_xor(ss, 1, 64);
  ss += __shfl_xor(ss, 2, 64);
  ss += __shfl_xor(ss, 4, 64);
  ss += __shfl_xor(ss, 8, 64);               // row sum-sq in its 16-lane group
  float scale = rsqrtf(ss) * (isU ? LOG2E : 1.0f);   // norms ~8; eps never binds
  short4 o;
  o.x = f32_bf16_rne(v.x * scale);
  o.y = f32_bf16_rne(v.y * scale);
  o.z = f32_bf16_rne(v.z * scale);
  o.w = f32_bf16_rne(v.w * scale);
  int lrow_g = isU ? row : (row - N);
  short* dst = isU ? (Ub + (size_t)lrow_g * D) : (Rb + (size_t)lrow_g * D);
  reinterpret_cast<short4*>(dst)[c] = o;
  // fragment-linear copy: tile = row/16; chunk = ks*64 + kgrp*16 + lrow,
  // ks = c>>3, kgrp = (c>>1)&3, half = c&1 (4 shorts per half-chunk)
  short* dst2 = isU ? Ubp : Rbp;
  size_t off2 = (size_t)(lrow_g >> 4) * 1024 +
                (size_t)(((c >> 3) * 64 + ((c >> 1) & 3) * 16 + lrow)) * 8 +
                (c & 1) * 4;
  *reinterpret_cast<short4*>(dst2 + off2) = o;
}

// Fused kernel. R26 change: 4-TILE STRIP with ZERO in-loop barriers — attacks
// the per-block fixed cost (the one category never varied: 4096 blocks x
// ~2K-cycle setup/ramp/barrier/epilogue for only 128 MFMAs each; R24/R25
// nulls rule out traffic, locality, transactions). Block = 128 rows x 512
// cols (by 0..63, cx 0..15): A fragments load ONCE per block; per tile only
// 8 contiguous B loads/wave; rowacc accumulates across the strip in regs;
// col partials per wave-pair go DIRECTLY to global (slice by*2+wr — no LDS,
// no barrier); row epilogue once per block (R21 shuffle-free rsp, 1 barrier).
// Per-wave: 48 loads / 128 MFMAs (was 16/32) — fixed costs amortized 4x.
// blocks 0..255:    scattered interactions (row-major copy, R11-verified).
// blocks 256..319:  column sums of Ub/Rb for S_cos (row-major copy).
// blocks 320..1343: gemm strip as above.
__global__ __launch_bounds__(256, 4) void mega_kernel(
    const short* __restrict__ Ub, const short* __restrict__ Rb,
    const short* __restrict__ Ubp, const short* __restrict__ Rbp,
    const float* __restrict__ ratings, const float* __restrict__ cossim,
    const int* __restrict__ u_idx, const int* __restrict__ i_idx,
    float* __restrict__ rowRMe, float* __restrict__ sumU,
    float* __restrict__ sumR, double* __restrict__ scal,
    float* __restrict__ rowpart, float* __restrict__ colpart) {
  __shared__ float rsp[128 * RSP_STRIDE];    // row partials; aux aliases front
  float* sm = rsp;
  const int bid = blockIdx.x;
  const int t = threadIdx.x;
  const int wid = t >> 6, lane = t & 63;

  if (bid >= 320) {
    const int g = bid - 320;                   // 0..1023
    const int by = g >> 4;                     // row block 0..63 (128 rows)
    const int cx = g & 15;                     // col strip 0..15 (512 cols)
    const int wr = wid >> 1, wc = wid & 1;
    const int lrow = lane & 15;   // fragment row (A) / col (B) index
    const int kgrp = lane >> 4;   // k-group

    const short8v* Uv = reinterpret_cast<const short8v*>(Ubp);
    const short8v* Rv = reinterpret_cast<const short8v*>(Rbp);

    // A fragments ONCE per block: tiles by*8 + wr*4 + m, contiguous 16B/lane
    short8v aF[4][2];
    #pragma unroll
    for (int m = 0; m < 4; ++m) {
      size_t tA = (size_t)(by * 8 + wr * 4 + m) * 128 + lane;
      aF[m][0] = Uv[tA];
      aF[m][1] = Uv[tA + 64];
    }

    float rowacc[4][4] = {};   // [m][reg] — accumulates across the whole strip

    #pragma unroll 1
    for (int ci = 0; ci < 4; ++ci) {
      // B fragments for this tile: col tiles cx*32 + ci*8 + wc*4 + n
      short8v bF[4][2];
      #pragma unroll
      for (int n = 0; n < 4; ++n) {
        size_t tB = (size_t)(cx * 32 + ci * 8 + wc * 4 + n) * 128 + lane;
        bF[n][0] = Rv[tB];
        bF[n][1] = Rv[tB + 64];
      }
      #pragma unroll
      for (int n = 0; n < 4; ++n) {
        f32x4 acc[4] = {};
        #pragma unroll
        for (int m = 0; m < 4; ++m)
          acc[m] = __builtin_amdgcn_mfma_f32_16x16x32_bf16(aF[m][0], bF[n][0], acc[m], 0, 0, 0);
        #pragma unroll
        for (int m = 0; m < 4; ++m)
          acc[m] = __builtin_amdgcn_mfma_f32_16x16x32_bf16(aF[m][1], bF[n][1], acc[m], 0, 0, 0);
        float p0 = 0.f, p1 = 0.f, p2 = 0.f, p3 = 0.f;
        #pragma unroll
        for (int r = 0; r < 4; ++r) {
          float e0 = fast_exp2(acc[0][r]); rowacc[0][r] += e0; p0 += e0;
          float e1 = fast_exp2(acc[1][r]); rowacc[1][r] += e1; p1 += e1;
          float e2 = fast_exp2(acc[2][r]); rowacc[2][r] += e2; p2 += e2;
          float e3 = fast_exp2(acc[3][r]); rowacc[3][r] += e3; p3 += e3;
        }
        float cacc = (p0 + p1) + (p2 + p3);
        cacc += __shfl_xor(cacc, 16, 64);      // combine 4 kgrp partials
        cacc += __shfl_xor(cacc, 32, 64);
        if (lane < 16)                          // direct global store, no LDS
          colpart[(size_t)(by * 2 + wr) * N +
                  cx * 512 + ci * 128 + wc * 64 + n * 16 + lane] = cacc;
      }
    }

    // row epilogue ONCE per block: per-lane partials to LDS, 1 barrier
    #pragma unroll
    for (int m = 0; m < 4; ++m)
      #pragma unroll
      for (int r = 0; r < 4; ++r)
        rsp[(wr * 64 + m * 16 + kgrp * 4 + r) * RSP_STRIDE + wc * 16 + lrow] =
            rowacc[m][r];
    __syncthreads();

    if (t < 128) {
      const float4* rp4 = reinterpret_cast<const float4*>(&rsp[t * RSP_STRIDE]);
      float4 s0 = rp4[0], s1 = rp4[1], s2 = rp4[2], s3 = rp4[3];
      float4 s4 = rp4[4], s5 = rp4[5], s6 = rp4[6], s7 = rp4[7];
      float a0 = (s0.x + s0.y) + (s0.z + s0.w);
      float a1 = (s1.x + s1.y) + (s1.z + s1.w);
      float a2 = (s2.x + s2.y) + (s2.z + s2.w);
      float a3 = (s3.x + s3.y) + (s3.z + s3.w);
      float a4 = (s4.x + s4.y) + (s4.z + s4.w);
      float a5 = (s5.x + s5.y) + (s5.z + s5.w);
      float a6 = (s6.x + s6.y) + (s6.z + s6.w);
      float a7 = (s7.x + s7.y) + (s7.z + s7.w);
      rowpart[(size_t)cx * N + by * 128 + t] =
          ((a0 + a1) + (a2 + a3)) + ((a4 + a5) + (a6 + a7));
    }

  } else if (bid < 256) {
    const int sb = bid;                        // 0..255, 256 pairs each
    const int grp = lane >> 3, sub = lane & 7;
    float exacc = 0.f, msacc = 0.f;
    #pragma unroll 2
    for (int pass = 0; pass < 8; ++pass) {
      const int p = sb * 256 + pass * 32 + wid * 8 + grp;   // pair id
      int u = u_idx[p], i = i_idx[p];
      short8v uv = *reinterpret_cast<const short8v*>(Ub + (size_t)u * D + sub * 8);
      short8v iv = *reinterpret_cast<const short8v*>(Rb + (size_t)i * D + sub * 8);
      float pd = 0.f;
      #pragma unroll
      for (int e = 0; e < 8; ++e)
        pd += bf16_to_f32((unsigned short)uv[e]) * bf16_to_f32((unsigned short)iv[e]);
      pd += __shfl_xor(pd, 1, 64);
      pd += __shfl_xor(pd, 2, 64);
      pd += __shfl_xor(pd, 4, 64);             // dot complete in all 8 lanes
      if (sub == 0) {
        float rv = ratings[p];
        exacc += (rv - FILL) * pd;             // scaled by log2e; fixed later
        float dd = rv - cossim[p];
        msacc += dd * dd;
        atomicAdd(&rowRMe[u], rv - FILL);      // spread over 8192 addresses
      }
    }
    exacc += __shfl_xor(exacc, 8, 64);
    exacc += __shfl_xor(exacc, 16, 64);
    exacc += __shfl_xor(exacc, 32, 64);
    msacc += __shfl_xor(msacc, 8, 64);
    msacc += __shfl_xor(msacc, 16, 64);
    msacc += __shfl_xor(msacc, 32, 64);
    if (lane == 0) { sm[wid] = exacc; sm[8 + wid] = msacc; }
    __syncthreads();
    if (t == 0)
      atomicAdd(&scal[1], (double)(sm[0] + sm[1] + sm[2] + sm[3]));
    else if (t == 64)
      atomicAdd(&scal[2], (double)(sm[8] + sm[9] + sm[10] + sm[11]));

  } else {
    // column sums. lane l reads row (base + l>>3), cols (l&7)*8..+7 as one
    // short8v; 8 passes of 32 rows per block.
    int sb = bid - 256;                    // 0..63
    const short* M = (sb < 32) ? Ub : Rb;
    float* dst = (sb < 32) ? sumU : sumR;
    int rbase = (sb & 31) * 256;
    float pc[8] = {};
    #pragma unroll
    for (int p = 0; p < 8; ++p) {
      int row = rbase + p * 32 + wid * 8 + (lane >> 3);
      short8v v = *reinterpret_cast<const short8v*>(M + (size_t)row * D + (lane & 7) * 8);
      #pragma unroll
      for (int e = 0; e < 8; ++e)
        pc[e] += bf16_to_f32((unsigned short)v[e]);
    }
    #pragma unroll
    for (int e = 0; e < 8; ++e) {
      pc[e] += __shfl_xor(pc[e], 8, 64);
      pc[e] += __shfl_xor(pc[e], 16, 64);
      pc[e] += __shfl_xor(pc[e], 32, 64);
    }
    if (lane < 8)
      #pragma unroll
      for (int e = 0; e < 8; ++e) sm[wid * 64 + lane * 8 + e] = pc[e];
    __syncthreads();
    if (t < 64)
      atomicAdd(&dst[t], sm[t] + sm[64 + t] + sm[128 + t] + sm[192 + t]);
  }
}

// 128 blocks x 64 rows; 4 thread-quarters per row reduce 4 row-slices +
// 32 col-slices each, LDS-combine, log term -> scal[3]. Last block
// (completion counter in scal[7]) computes the final scalar output.
__global__ __launch_bounds__(256) void final_out_kernel(
    const float* __restrict__ rowpart, const float* __restrict__ colpart,
    const float* __restrict__ rowRMe, const float* __restrict__ sumU,
    const float* __restrict__ sumR, double* __restrict__ scal,
    float* __restrict__ out) {
  __shared__ float smr[256];
  __shared__ float smc[256];
  __shared__ unsigned int done;
  const int t = threadIdx.x;
  const int q = t >> 6, r = t & 63;          // quarter, row-in-block
  const int i = blockIdx.x * 64 + r;
  float rsum = 0.f, csum = 0.f;
  #pragma unroll
  for (int p = q * 4; p < q * 4 + 4; ++p) rsum += rowpart[(size_t)p * N + i];
  #pragma unroll 8
  for (int p = q * 32; p < q * 32 + 32; ++p) csum += colpart[(size_t)p * N + i];
  smr[t] = rsum; smc[t] = csum;
  __syncthreads();
  if (t < 64) {
    rsum = smr[t] + smr[64 + t] + smr[128 + t] + smr[192 + t];
    csum = smc[t] + smc[64 + t] + smc[128 + t] + smc[192 + t];
    float term = (FILL * (float)N + rowRMe[i]) * 0.5f * (logf(rsum) + logf(csum));
    float s = wave_reduce_sum(term);
    if (t == 0) {
      atomicAdd(&scal[3], (double)s);
      __threadfence();
    }
  }
  __syncthreads();
  unsigned int* cnt = (unsigned int*)(scal + 7);
  if (t == 0) {
    __threadfence();
    done = atomicAdd(cnt, 1u);
  }
  __syncthreads();
  if (done == 127 && t < 64) {               // last of 128 blocks finishes up
    __threadfence();
    float p = sumU[t] * sumR[t];
    p = wave_reduce_sum(p);                  // = log2e * sum(cos)
    if (t == 0) {
      double T = (0.1 * (double)p + scal[1]) * LN2;   // undo log2e scaling
      double contrastive = (scal[3] - T) / (double)N;
      double mse = scal[2] / (double)B_PAIRS;
      out[0] = (float)(0.5 * contrastive + 0.5 * mse);
      *cnt = 0u;                             // leave counter clean for replay
    }
  }
}

extern "C" void kernel_launch(void* const* d_in, const int* in_sizes, int n_in,
                              void* d_out, int out_size, void* d_ws, size_t ws_size,
                              hipStream_t stream) {
  const float* U       = (const float*)d_in[0];
  const float* R       = (const float*)d_in[1];
  const float* ratings = (const float*)d_in[2];
  const float* cossim  = (const float*)d_in[3];
  const int*   u_idx   = (const int*)d_in[4];
  const int*   i_idx   = (const int*)d_in[5];

  float* ws      = (float*)d_ws;
  float* rowRMe  = ws;                      // [8192]
  float* sumU    = ws + 8192;               // [64]
  float* sumR    = ws + 8256;               // [64]
  double* scal   = (double*)(ws + 8320);    // 8 doubles; [7] = completion counter
  short* Ub      = (short*)(ws + 8448);     // [N*D] bf16 row-major (log2e on U)
  short* Rb      = Ub + (size_t)N * D;      // [N*D] bf16 row-major
  float* rowpart = ws + 532736;             // [16][8192]  slice per col-strip cx
  float* colpart = ws + 663808;             // [128][8192] slice per (by*2+wr)
  short* Ubp     = (short*)(ws + 1712384);  // [N*D] bf16 fragment-linear
  short* Rbp     = Ubp + (size_t)N * D;     // [N*D] bf16 fragment-linear
  // total ws use: 2236672 floats ≈ 8.9 MB

  norm_kernel<<<(2 * N) / 16, 256, 0, stream>>>(U, R, Ub, Rb, Ubp, Rbp,
                                                rowRMe, sumU, sumR, scal);

  mega_kernel<<<1344, 256, 0, stream>>>(Ub, Rb, Ubp, Rbp, ratings, cossim,
                                        u_idx, i_idx, rowRMe, sumU, sumR, scal,
                                        rowpart, colpart);

  final_out_kernel<<<128, 256, 0, stream>>>(rowpart, colpart, rowRMe,
                                            sumU, sumR, scal, (float*)d_out);
}

// Round 27
// 38.805 us; speedup vs baseline: 1.4814x; 1.4814x over previous
//
#include <hip/hip_runtime.h>
#include <hip/hip_bf16.h>

#define N 8192        // n_users == n_recipes (required by reference broadcasting)
#define D 64
#define B_PAIRS 65536
#define FILL 0.1f
#define LOG2E 1.4426950408889634f
#define LN2 0.6931471805599453
#define RSP_STRIDE 36   // row-partial LDS stride (floats): 16B-aligned, 2-way banks
#define CSP_STRIDE 65   // col-partial LDS stride

typedef __attribute__((ext_vector_type(8))) short short8v;   // 8 bf16 in 4 VGPRs
typedef __attribute__((ext_vector_type(4))) float f32x4;

__device__ __forceinline__ float wave_reduce_sum(float v) {
  #pragma unroll
  for (int m = 1; m < 64; m <<= 1) v += __shfl_xor(v, m, 64);
  return v;
}

__device__ __forceinline__ float bf16_to_f32(unsigned short u) {
  unsigned int b = ((unsigned int)u) << 16;
  return __builtin_bit_cast(float, b);
}

__device__ __forceinline__ short f32_bf16_rne(float f) {
  unsigned int b = __builtin_bit_cast(unsigned int, f);
  return (short)((b + 0x7FFFu + ((b >> 16) & 1u)) >> 16);
}

// v_exp_f32 via builtin (compiler handles the trans-op wait states; raw asm
// without s_nop corrupted results in R8). Args bounded: |x| <= ~1.45.
__device__ __forceinline__ float fast_exp2(float x) {
#if __has_builtin(__builtin_amdgcn_exp2f)
  return __builtin_amdgcn_exp2f(x);
#else
  float r;
  asm("v_exp_f32 %0, %1\n\ts_nop 1" : "=v"(r) : "v"(x));
  return r;
#endif
}

// Vectorized norm. Emits TWO copies of the normalized bf16 rows:
//  (a) row-major (for the scatter/colsum aux sections), and
//  (b) FRAGMENT-LINEAR: each 16-row tile stored chunk-order (ks,kgrp,lrow)
//      so a gemm fragment load is base + lane*16B (R23: -27% total).
// U side pre-scaled by log2(e) so the gemm uses raw exp2.
// Side duty: zero-init accumulators + completion counter (replay-safe).
__global__ __launch_bounds__(256) void norm_kernel(const float* __restrict__ U,
                                                   const float* __restrict__ R,
                                                   short* __restrict__ Ub,
                                                   short* __restrict__ Rb,
                                                   short* __restrict__ Ubp,
                                                   short* __restrict__ Rbp,
                                                   float* __restrict__ rowRMe,
                                                   float* __restrict__ sumU,
                                                   float* __restrict__ sumR,
                                                   double* __restrict__ scal) {
  const int t = threadIdx.x;
  const int b = blockIdx.x;
  if (b < 32) {
    rowRMe[b * 256 + t] = 0.f;
  } else if (b == 32) {
    if (t < 64) sumU[t] = 0.f;
    else if (t < 128) sumR[t - 64] = 0.f;
    else if (t < 136) scal[t - 128] = 0.0;   // scal[0..7]; [7] doubles as counter
  }
  int row = b * 16 + (t >> 4);               // 16 rows/block
  int c = t & 15;                            // float4 index within row (k=4c..4c+3)
  bool isU = row < N;
  int lrow = row & 15;
  const float* src = isU ? (U + (size_t)row * D) : (R + (size_t)(row - N) * D);
  float4 v = reinterpret_cast<const float4*>(src)[c];
  float ss = v.x * v.x + v.y * v.y + v.z * v.z + v.w * v.w;
  ss += __shfl_xor(ss, 1, 64);
  ss += __shfl_xor(ss, 2, 64);
  ss += __shfl_xor(ss, 4, 64);
  ss += __shfl_xor(ss, 8, 64);               // row sum-sq in its 16-lane group
  float scale = rsqrtf(ss) * (isU ? LOG2E : 1.0f);   // norms ~8; eps never binds
  short4 o;
  o.x = f32_bf16_rne(v.x * scale);
  o.y = f32_bf16_rne(v.y * scale);
  o.z = f32_bf16_rne(v.z * scale);
  o.w = f32_bf16_rne(v.w * scale);
  int lrow_g = isU ? row : (row - N);
  short* dst = isU ? (Ub + (size_t)lrow_g * D) : (Rb + (size_t)lrow_g * D);
  reinterpret_cast<short4*>(dst)[c] = o;
  // fragment-linear copy: tile = row/16; chunk = ks*64 + kgrp*16 + lrow,
  // ks = c>>3, kgrp = (c>>1)&3, half = c&1 (4 shorts per half-chunk)
  short* dst2 = isU ? Ubp : Rbp;
  size_t off2 = (size_t)(lrow_g >> 4) * 1024 +
                (size_t)(((c >> 3) * 64 + ((c >> 1) & 3) * 16 + lrow)) * 8 +
                (c & 1) * 4;
  *reinterpret_cast<short4*>(dst2 + off2) = o;
}

// Fused kernel (R24 configuration — best measured: 38.95us total).
// Conflict-free LDS staging of fragment-linear panels: one linear 32KB stage
// per 128x128 block (perfect 16B/lane memcpy), fragments read from LDS at
// lane*16B (conflict-free by layout), shuffle-free epilogue via plain LDS
// partials, coalesced partial stores. R25 (XCD banding) and R26 (4-tile
// strip) both measured worse — this is the validated optimum.
// blocks 0..255:    scattered interactions (row-major copy, R11-verified).
// blocks 256..319:  column sums of Ub/Rb for S_cos (row-major copy).
// blocks 320..4415: gemm 128x128, 4 waves 2x2, staged fragment-linear loads,
//                   fused exp, shuffle-free epilogue, coalesced stores.
__global__ __launch_bounds__(256, 4) void mega_kernel(
    const short* __restrict__ Ub, const short* __restrict__ Rb,
    const short* __restrict__ Ubp, const short* __restrict__ Rbp,
    const float* __restrict__ ratings, const float* __restrict__ cossim,
    const int* __restrict__ u_idx, const int* __restrict__ i_idx,
    float* __restrict__ rowRMe, float* __restrict__ sumU,
    float* __restrict__ sumR, double* __restrict__ scal,
    float* __restrict__ rowpart, float* __restrict__ colpart) {
  // 32KB pool: gemm stage (2048 short8v) THEN reused as partial pool after
  // barrier #2; aux sections alias the front as sm[256].
  __shared__ short8v lds_stage[2048];
  float* pool = reinterpret_cast<float*>(lds_stage);
  float* rsp = pool;                         // [row 0..127][slot 0..31] pad 36
  float* csp = pool + 128 * RSP_STRIDE;      // [wid*4+kgrp][col64] pad 65
  float* sm  = pool;                         // aux scratch alias
  const int bid = blockIdx.x;
  const int t = threadIdx.x;
  const int wid = t >> 6, lane = t & 63;

  if (bid >= 320) {
    const int g = bid - 320;
    const int cx = g & 63, by = g >> 6;
    const int wr = wid >> 1, wc = wid & 1;
    const int lrow = lane & 15;   // fragment row (A) / col (B) index
    const int kgrp = lane >> 4;   // k-group: k = ks*32 + kgrp*8 + j

    // stage A panel (16KB, contiguous in Ubp) + B panel into LDS: pure memcpy
    {
      const short8v* Ag = reinterpret_cast<const short8v*>(Ubp + (size_t)by * 8192);
      const short8v* Bg = reinterpret_cast<const short8v*>(Rbp + (size_t)cx * 8192);
      short8v* Al = lds_stage;
      short8v* Bl = lds_stage + 1024;
      #pragma unroll
      for (int i = 0; i < 4; ++i) {
        Al[i * 256 + t] = Ag[i * 256 + t];
        Bl[i * 256 + t] = Bg[i * 256 + t];
      }
    }
    __syncthreads();

    // fragment reads from LDS: lane*16B stride within each 1KB half-chunk
    const short8v* Aw = lds_stage + (size_t)(wr * 4) * 128 + lane;
    const short8v* Bw = lds_stage + 1024 + (size_t)(wc * 4) * 128 + lane;
    short8v aF[4][2], bF[4][2];
    #pragma unroll
    for (int m = 0; m < 4; ++m) {
      aF[m][0] = Aw[m * 128];
      bF[m][0] = Bw[m * 128];
      aF[m][1] = Aw[m * 128 + 64];
      bF[m][1] = Bw[m * 128 + 64];
    }
    __syncthreads();   // all fragments in registers -> LDS reusable as pool

    float rowacc[4][4] = {};   // [m][reg]
    #pragma unroll
    for (int n = 0; n < 4; ++n) {
      f32x4 acc[4] = {};
      #pragma unroll
      for (int m = 0; m < 4; ++m)
        acc[m] = __builtin_amdgcn_mfma_f32_16x16x32_bf16(aF[m][0], bF[n][0], acc[m], 0, 0, 0);
      #pragma unroll
      for (int m = 0; m < 4; ++m)
        acc[m] = __builtin_amdgcn_mfma_f32_16x16x32_bf16(aF[m][1], bF[n][1], acc[m], 0, 0, 0);
      float p0 = 0.f, p1 = 0.f, p2 = 0.f, p3 = 0.f;
      #pragma unroll
      for (int r = 0; r < 4; ++r) {
        float e0 = fast_exp2(acc[0][r]); rowacc[0][r] += e0; p0 += e0;
        float e1 = fast_exp2(acc[1][r]); rowacc[1][r] += e1; p1 += e1;
        float e2 = fast_exp2(acc[2][r]); rowacc[2][r] += e2; p2 += e2;
        float e3 = fast_exp2(acc[3][r]); rowacc[3][r] += e3; p3 += e3;
      }
      // per-lane partial col sum: plain LDS write, unique slot, no shuffle
      csp[(wid * 4 + kgrp) * CSP_STRIDE + n * 16 + lrow] = (p0 + p1) + (p2 + p3);
    }

    // per-lane partial row sums: unique slot per (blockrow, wc, lrow)
    #pragma unroll
    for (int m = 0; m < 4; ++m)
      #pragma unroll
      for (int r = 0; r < 4; ++r)
        rsp[(wr * 64 + m * 16 + kgrp * 4 + r) * RSP_STRIDE + wc * 16 + lrow] =
            rowacc[m][r];

    __syncthreads();   // all partials written -> store phase

    if (t < 128) {
      // row t: sum its 32 partials (8x ds_read_b128, independent, tree add)
      const float4* rp4 = reinterpret_cast<const float4*>(&rsp[t * RSP_STRIDE]);
      float4 s0 = rp4[0], s1 = rp4[1], s2 = rp4[2], s3 = rp4[3];
      float4 s4 = rp4[4], s5 = rp4[5], s6 = rp4[6], s7 = rp4[7];
      float a0 = (s0.x + s0.y) + (s0.z + s0.w);
      float a1 = (s1.x + s1.y) + (s1.z + s1.w);
      float a2 = (s2.x + s2.y) + (s2.z + s2.w);
      float a3 = (s3.x + s3.y) + (s3.z + s3.w);
      float a4 = (s4.x + s4.y) + (s4.z + s4.w);
      float a5 = (s5.x + s5.y) + (s5.z + s5.w);
      float a6 = (s6.x + s6.y) + (s6.z + s6.w);
      float a7 = (s7.x + s7.y) + (s7.z + s7.w);
      rowpart[(size_t)cx * N + by * 128 + t] =
          ((a0 + a1) + (a2 + a3)) + ((a4 + a5) + (a6 + a7));
    } else {
      // col c: sum 8 partials (waves {half, half+2} x 4 kgrps), independent reads
      int c = t - 128;
      int half = c >> 6, c64 = c & 63;
      float csum = 0.f;
      #pragma unroll
      for (int kg = 0; kg < 4; ++kg) {
        csum += csp[(half * 4 + kg) * CSP_STRIDE + c64];
        csum += csp[((half + 2) * 4 + kg) * CSP_STRIDE + c64];
      }
      colpart[(size_t)by * N + cx * 128 + c] = csum;
    }

  } else if (bid < 256) {
    const int sb = bid;                        // 0..255, 256 pairs each
    const int grp = lane >> 3, sub = lane & 7;
    float exacc = 0.f, msacc = 0.f;
    #pragma unroll 2
    for (int pass = 0; pass < 8; ++pass) {
      const int p = sb * 256 + pass * 32 + wid * 8 + grp;   // pair id
      int u = u_idx[p], i = i_idx[p];
      short8v uv = *reinterpret_cast<const short8v*>(Ub + (size_t)u * D + sub * 8);
      short8v iv = *reinterpret_cast<const short8v*>(Rb + (size_t)i * D + sub * 8);
      float pd = 0.f;
      #pragma unroll
      for (int e = 0; e < 8; ++e)
        pd += bf16_to_f32((unsigned short)uv[e]) * bf16_to_f32((unsigned short)iv[e]);
      pd += __shfl_xor(pd, 1, 64);
      pd += __shfl_xor(pd, 2, 64);
      pd += __shfl_xor(pd, 4, 64);             // dot complete in all 8 lanes
      if (sub == 0) {
        float rv = ratings[p];
        exacc += (rv - FILL) * pd;             // scaled by log2e; fixed later
        float dd = rv - cossim[p];
        msacc += dd * dd;
        atomicAdd(&rowRMe[u], rv - FILL);      // spread over 8192 addresses
      }
    }
    exacc += __shfl_xor(exacc, 8, 64);
    exacc += __shfl_xor(exacc, 16, 64);
    exacc += __shfl_xor(exacc, 32, 64);
    msacc += __shfl_xor(msacc, 8, 64);
    msacc += __shfl_xor(msacc, 16, 64);
    msacc += __shfl_xor(msacc, 32, 64);
    if (lane == 0) { sm[wid] = exacc; sm[8 + wid] = msacc; }
    __syncthreads();
    if (t == 0)
      atomicAdd(&scal[1], (double)(sm[0] + sm[1] + sm[2] + sm[3]));
    else if (t == 64)
      atomicAdd(&scal[2], (double)(sm[8] + sm[9] + sm[10] + sm[11]));

  } else {
    // column sums. lane l reads row (base + l>>3), cols (l&7)*8..+7 as one
    // short8v; 8 passes of 32 rows per block.
    int sb = bid - 256;                    // 0..63
    const short* M = (sb < 32) ? Ub : Rb;
    float* dst = (sb < 32) ? sumU : sumR;
    int rbase = (sb & 31) * 256;
    float pc[8] = {};
    #pragma unroll
    for (int p = 0; p < 8; ++p) {
      int row = rbase + p * 32 + wid * 8 + (lane >> 3);
      short8v v = *reinterpret_cast<const short8v*>(M + (size_t)row * D + (lane & 7) * 8);
      #pragma unroll
      for (int e = 0; e < 8; ++e)
        pc[e] += bf16_to_f32((unsigned short)v[e]);
    }
    #pragma unroll
    for (int e = 0; e < 8; ++e) {
      pc[e] += __shfl_xor(pc[e], 8, 64);
      pc[e] += __shfl_xor(pc[e], 16, 64);
      pc[e] += __shfl_xor(pc[e], 32, 64);
    }
    if (lane < 8)
      #pragma unroll
      for (int e = 0; e < 8; ++e) sm[wid * 64 + lane * 8 + e] = pc[e];
    __syncthreads();
    if (t < 64)
      atomicAdd(&dst[t], sm[t] + sm[64 + t] + sm[128 + t] + sm[192 + t]);
  }
}

// 128 blocks x 64 rows; 4 thread-quarters per row reduce 16 row-slices +
// 16 col-slices each, LDS-combine, log term -> scal[3]. Last block
// (completion counter in scal[7]) computes the final scalar output.
__global__ __launch_bounds__(256) void final_out_kernel(
    const float* __restrict__ rowpart, const float* __restrict__ colpart,
    const float* __restrict__ rowRMe, const float* __restrict__ sumU,
    const float* __restrict__ sumR, double* __restrict__ scal,
    float* __restrict__ out) {
  __shared__ float smr[256];
  __shared__ float smc[256];
  __shared__ unsigned int done;
  const int t = threadIdx.x;
  const int q = t >> 6, r = t & 63;          // quarter, row-in-block
  const int i = blockIdx.x * 64 + r;
  float rsum = 0.f, csum = 0.f;
  #pragma unroll 8
  for (int p = q * 16; p < q * 16 + 16; ++p) {
    rsum += rowpart[(size_t)p * N + i];
    csum += colpart[(size_t)p * N + i];
  }
  smr[t] = rsum; smc[t] = csum;
  __syncthreads();
  if (t < 64) {
    rsum = smr[t] + smr[64 + t] + smr[128 + t] + smr[192 + t];
    csum = smc[t] + smc[64 + t] + smc[128 + t] + smc[192 + t];
    float term = (FILL * (float)N + rowRMe[i]) * 0.5f * (logf(rsum) + logf(csum));
    float s = wave_reduce_sum(term);
    if (t == 0) {
      atomicAdd(&scal[3], (double)s);
      __threadfence();
    }
  }
  __syncthreads();
  unsigned int* cnt = (unsigned int*)(scal + 7);
  if (t == 0) {
    __threadfence();
    done = atomicAdd(cnt, 1u);
  }
  __syncthreads();
  if (done == 127 && t < 64) {               // last of 128 blocks finishes up
    __threadfence();
    float p = sumU[t] * sumR[t];
    p = wave_reduce_sum(p);                  // = log2e * sum(cos)
    if (t == 0) {
      double T = (0.1 * (double)p + scal[1]) * LN2;   // undo log2e scaling
      double contrastive = (scal[3] - T) / (double)N;
      double mse = scal[2] / (double)B_PAIRS;
      out[0] = (float)(0.5 * contrastive + 0.5 * mse);
      *cnt = 0u;                             // leave counter clean for replay
    }
  }
}

extern "C" void kernel_launch(void* const* d_in, const int* in_sizes, int n_in,
                              void* d_out, int out_size, void* d_ws, size_t ws_size,
                              hipStream_t stream) {
  const float* U       = (const float*)d_in[0];
  const float* R       = (const float*)d_in[1];
  const float* ratings = (const float*)d_in[2];
  const float* cossim  = (const float*)d_in[3];
  const int*   u_idx   = (const int*)d_in[4];
  const int*   i_idx   = (const int*)d_in[5];

  float* ws      = (float*)d_ws;
  float* rowRMe  = ws;                      // [8192]
  float* sumU    = ws + 8192;               // [64]
  float* sumR    = ws + 8256;               // [64]
  double* scal   = (double*)(ws + 8320);    // 8 doubles; [7] = completion counter
  short* Ub      = (short*)(ws + 8448);     // [N*D] bf16 row-major (log2e on U)
  short* Rb      = Ub + (size_t)N * D;      // [N*D] bf16 row-major
  float* rowpart = ws + 532736;             // [64][8192] slice per col-tile cx
  float* colpart = ws + 1057024;            // [64][8192] slice per row-tile by
  short* Ubp     = (short*)(ws + 1581312);  // [N*D] bf16 fragment-linear
  short* Rbp     = Ubp + (size_t)N * D;     // [N*D] bf16 fragment-linear
  // total ws use: 2105600 floats ≈ 8.4 MB

  norm_kernel<<<(2 * N) / 16, 256, 0, stream>>>(U, R, Ub, Rb, Ubp, Rbp,
                                                rowRMe, sumU, sumR, scal);

  mega_kernel<<<4416, 256, 0, stream>>>(Ub, Rb, Ubp, Rbp, ratings, cossim,
                                        u_idx, i_idx, rowRMe, sumU, sumR, scal,
                                        rowpart, colpart);

  final_out_kernel<<<128, 256, 0, stream>>>(rowpart, colpart, rowRMe,
                                            sumU, sumR, scal, (float*)d_out);
}